// Round 7
// baseline (818.050 us; speedup 1.0000x reference)
//
#include <hip/hip_runtime.h>

#define D 128
#define COARSE 128          // nodes per coarse bin (LDS tile rows)
#define NBMAX 400           // >= ceil(50000/128)=391
#define CHUNK 4096          // edges per block in cnt/part passes

typedef __attribute__((ext_vector_type(8))) short short8;
typedef __attribute__((ext_vector_type(8))) unsigned short ushort8;
typedef __attribute__((ext_vector_type(4))) float f32x4;

// round-to-nearest-even f32 -> bf16 bits
__device__ __forceinline__ unsigned short f2bf(float f) {
    unsigned u = __float_as_uint(f);
    unsigned r = (u + 0x7fffu + ((u >> 16) & 1u)) >> 16;
    return (unsigned short)r;
}

// ---------- 0. x -> bf16 copy (shared by seg gather + gemm A-stage) ----------
__global__ void xbf_k(const float* __restrict__ x, unsigned short* __restrict__ xbf,
                      int total8) {
    int i = blockIdx.x * 256 + threadIdx.x;      // one thread = 8 elements
    if (i >= total8) return;
    const float4* p = (const float4*)x + (size_t)i * 2;
    float4 a = p[0], b = p[1];
    ushort8 v;
    v[0] = f2bf(a.x); v[1] = f2bf(a.y); v[2] = f2bf(a.z); v[3] = f2bf(a.w);
    v[4] = f2bf(b.x); v[5] = f2bf(b.y); v[6] = f2bf(b.z); v[7] = f2bf(b.w);
    *(ushort8*)(xbf + (size_t)i * 8) = v;
}

// ---------- 1. prepass: B^T bf16. BT[col][k], k-contiguous per col ----------
__global__ void bt_k(const float* __restrict__ W, const float* __restrict__ M,
                     unsigned short* __restrict__ BT) {
    int g = blockIdx.x * 256 + threadIdx.x;     // 0..4095
    int col = g >> 5;
    int k0  = (g & 31) * 8;
    ushort8 hv;
#pragma unroll
    for (int j = 0; j < 8; ++j) {
        int k = k0 + j;
        float v = (k < 128) ? W[k * 128 + col] : M[(k - 128) * 128 + col];
        hv[j] = f2bf(v);
    }
    *(ushort8*)(BT + col * 256 + k0) = hv;
}

// ---------- 2. coarse histogram (LDS-privatized, ~NB atomics per block) ----------
__global__ void cnt_k(const int* __restrict__ dst, int nE, int NB,
                      int* __restrict__ chist) {
    __shared__ int lh[NBMAX];
    for (int t = threadIdx.x; t < NB; t += 256) lh[t] = 0;
    __syncthreads();
    int base = blockIdx.x * CHUNK;
#pragma unroll
    for (int r = 0; r < CHUNK / 256; ++r) {
        int i = base + r * 256 + threadIdx.x;
        if (i < nE) atomicAdd(&lh[dst[i] >> 7], 1);
    }
    __syncthreads();
    for (int t = threadIdx.x; t < NB; t += 256)
        if (lh[t]) atomicAdd(&chist[t], lh[t]);
}

// ---------- 3. scan coarse bins (single wave) ----------
__global__ void scanc_k(const int* __restrict__ chist, int NB,
                        int* __restrict__ cbeg, int* __restrict__ ccur) {
    int lane = threadIdx.x;
    if (lane >= 64) return;
    int carry = 0;
    int nch = (NB + 63) / 64;
    for (int c = 0; c < nch; ++c) {
        int i = c * 64 + lane;
        int v = (i < NB) ? chist[i] : 0;
        int incl = v;
#pragma unroll
        for (int off = 1; off < 64; off <<= 1) {
            int t = __shfl_up(incl, off, 64);
            if (lane >= off) incl += t;
        }
        int excl = carry + incl - v;
        if (i < NB) { cbeg[i] = excl; ccur[i] = excl; }
        carry += __shfl(incl, 63, 64);
    }
    if (lane == 0) cbeg[NB] = carry;
}

// ---------- 4. partition edges into coarse bins, packed (src16|dlow7) ----------
// One atomic per (block,bin) to reserve; per-edge ranks via LDS atomics; each
// block's writes per bin are contiguous -> no cross-XCD 64B-line ping-pong.
__global__ void part_k(const int* __restrict__ src, const int* __restrict__ dst,
                       int nE, int NB, int* __restrict__ ccur,
                       unsigned int* __restrict__ epk) {
    __shared__ int lcnt[NBMAX];
    __shared__ int lbase[NBMAX];
    __shared__ int lcur[NBMAX];
    for (int t = threadIdx.x; t < NB; t += 256) { lcnt[t] = 0; lcur[t] = 0; }
    __syncthreads();
    int base = blockIdx.x * CHUNK;
#pragma unroll
    for (int r = 0; r < CHUNK / 256; ++r) {
        int i = base + r * 256 + threadIdx.x;
        if (i < nE) atomicAdd(&lcnt[dst[i] >> 7], 1);
    }
    __syncthreads();
    for (int t = threadIdx.x; t < NB; t += 256)
        if (lcnt[t]) lbase[t] = atomicAdd(&ccur[t], lcnt[t]);
    __syncthreads();
#pragma unroll
    for (int r = 0; r < CHUNK / 256; ++r) {
        int i = base + r * 256 + threadIdx.x;
        if (i < nE) {
            int d = dst[i], b = d >> 7;
            int rk = atomicAdd(&lcur[b], 1);
            epk[lbase[b] + rk] = (unsigned)(src[i] & 0xFFFF) | ((unsigned)(d & 127) << 16);
        }
    }
}

// ---------- 5. segment sum per coarse bin: LDS f32 tile + ds_add_f32 ----------
// Block b owns nodes [b*128, b*128+128); gathers bf16 x rows (256B/row,
// u32/lane) and accumulates via LDS float atomics; writes tile out as bf16.
__global__ __launch_bounds__(512) void seg_k(
    const unsigned short* __restrict__ xbf, const int* __restrict__ cbeg,
    const unsigned int* __restrict__ epk, unsigned short* __restrict__ sbf,
    int nNodes) {
    __shared__ float st[COARSE][D];   // 64 KB
    int tid = threadIdx.x;
    for (int t = tid; t < COARSE * D / 4; t += 512)
        ((float4*)&st[0][0])[t] = make_float4(0.f, 0.f, 0.f, 0.f);
    __syncthreads();

    int b  = blockIdx.x;
    int e0 = cbeg[b], e1 = cbeg[b + 1];
    int w = tid >> 6, lane = tid & 63;
    int L = e1 - e0;
    int per = (L + 7) >> 3;                       // 8 waves
    int s0 = e0 + w * per;
    int s1 = s0 + per; if (s1 > e1) s1 = e1;

    int e = s0;
    for (; e + 2 <= s1; e += 2) {                 // 2-deep ILP on the gather
        unsigned pk0 = epk[e], pk1 = epk[e + 1];
        int j0 = pk0 & 0xFFFF, r0 = (pk0 >> 16) & 127;
        int j1 = pk1 & 0xFFFF, r1 = (pk1 >> 16) & 127;
        unsigned v0 = ((const unsigned*)(xbf + (size_t)j0 * D))[lane];
        unsigned v1 = ((const unsigned*)(xbf + (size_t)j1 * D))[lane];
        atomicAdd(&st[r0][2 * lane + 0], __uint_as_float(v0 << 16));
        atomicAdd(&st[r0][2 * lane + 1], __uint_as_float(v0 & 0xFFFF0000u));
        atomicAdd(&st[r1][2 * lane + 0], __uint_as_float(v1 << 16));
        atomicAdd(&st[r1][2 * lane + 1], __uint_as_float(v1 & 0xFFFF0000u));
    }
    for (; e < s1; ++e) {
        unsigned pk = epk[e];
        int j = pk & 0xFFFF, rr = (pk >> 16) & 127;
        unsigned v = ((const unsigned*)(xbf + (size_t)j * D))[lane];
        atomicAdd(&st[rr][2 * lane + 0], __uint_as_float(v << 16));
        atomicAdd(&st[rr][2 * lane + 1], __uint_as_float(v & 0xFFFF0000u));
    }
    __syncthreads();

    int rbase = b * COARSE;
    for (int t = tid; t < COARSE * D / 8; t += 512) {   // 2048 ushort8 stores
        int row = t >> 4, k8 = (t & 15) * 8;
        if (rbase + row < nNodes) {
            const float* sp = &st[row][k8];
            ushort8 v;
#pragma unroll
            for (int j = 0; j < 8; ++j) v[j] = f2bf(sp[j]);
            *(ushort8*)(sbf + (size_t)(rbase + row) * D + k8) = v;
        }
    }
}

// ---------- 6. out = relu([x|s] @ [W;M]) via bf16 MFMA (A staged from bf16) ----------
__global__ __launch_bounds__(256, 2) void gemm_mfma_k(
    const unsigned short* __restrict__ xbf, const unsigned short* __restrict__ sbf,
    const unsigned short* __restrict__ BT,
    float* __restrict__ out, int nNodes)
{
    __shared__ unsigned short Alds[64 * 256];   // [row][k] bf16, 32 KB
    char* Ab = (char*)Alds;

    const int tid  = threadIdx.x;
    const int lane = tid & 63;
    const int wv   = tid >> 6;          // 0..3
    const int r0   = blockIdx.x * 64;
    const int wcol = wv * 32;

    // ---- stage A = [xbf | sbf] rows r0..r0+63, swizzled: byte ^= (row&7)<<4 ----
#pragma unroll
    for (int h = 0; h < 2; ++h) {
        const unsigned short* srcp = h ? sbf : xbf;
#pragma unroll
        for (int it = 0; it < 4; ++it) {
            int q   = tid + it * 256;          // 0..1023 ushort8 slots
            int row = q >> 4;                  // 0..63
            int k8  = (q & 15) * 8;            // 0..120
            ushort8 v = (ushort8){0, 0, 0, 0, 0, 0, 0, 0};
            if (r0 + row < nNodes)
                v = *(const ushort8*)(srcp + (size_t)(r0 + row) * D + k8);
            int byte = (row * 512 + (h * 128 + k8) * 2) ^ ((row & 7) << 4);
            *(ushort8*)(Ab + byte) = v;
        }
    }
    __syncthreads();

    f32x4 acc[4][2];
#pragma unroll
    for (int rg = 0; rg < 4; ++rg)
#pragma unroll
        for (int cg = 0; cg < 2; ++cg)
            acc[rg][cg] = (f32x4){0.f, 0.f, 0.f, 0.f};

    const int l16  = lane & 15;
    const int lk8  = (lane >> 4) * 8;

#pragma unroll
    for (int t = 0; t < 8; ++t) {
        short8 bh[2];
#pragma unroll
        for (int cg = 0; cg < 2; ++cg) {
            int col = wcol + cg * 16 + l16;
            bh[cg] = *(const short8*)(BT + col * 256 + t * 32 + lk8);
        }
        short8 ah[4];
#pragma unroll
        for (int rg = 0; rg < 4; ++rg) {
            int row  = rg * 16 + l16;
            int byte = (row * 512 + (t * 32 + lk8) * 2) ^ ((row & 7) << 4);
            ah[rg] = *(const short8*)(Ab + byte);
        }
#pragma unroll
        for (int rg = 0; rg < 4; ++rg)
#pragma unroll
            for (int cg = 0; cg < 2; ++cg)
                acc[rg][cg] = __builtin_amdgcn_mfma_f32_16x16x32_bf16(ah[rg], bh[cg], acc[rg][cg], 0, 0, 0);
    }

    // ---- epilogue: relu + store. C/D: col = lane&15, row = (lane>>4)*4 + reg ----
    const int rowoff = (lane >> 4) * 4;
#pragma unroll
    for (int rg = 0; rg < 4; ++rg) {
#pragma unroll
        for (int r = 0; r < 4; ++r) {
            int row = r0 + rg * 16 + rowoff + r;
            if (row < nNodes) {
#pragma unroll
                for (int cg = 0; cg < 2; ++cg) {
                    float v = acc[rg][cg][r];
                    out[(size_t)row * D + wcol + cg * 16 + l16] = v > 0.f ? v : 0.f;
                }
            }
        }
    }
}

extern "C" void kernel_launch(void* const* d_in, const int* in_sizes, int n_in,
                              void* d_out, int out_size, void* d_ws, size_t ws_size,
                              hipStream_t stream) {
    const float* x = (const float*)d_in[0];
    const float* W = (const float*)d_in[1];
    const float* M = (const float*)d_in[2];
    const int* edges = (const int*)d_in[3];

    int N  = in_sizes[0] / D;        // 50000
    int nE = in_sizes[3] / 2;        // 800000
    const int* src = edges;          // edges[0, :]
    const int* dst = edges + nE;     // edges[1, :]
    float* out = (float*)d_out;
    int NB = (N + COARSE - 1) / COARSE;   // 391

    // workspace layout
    char* w = (char*)d_ws;
    unsigned short* xbf = (unsigned short*)w; w += (size_t)N * D * sizeof(unsigned short);  // 12.8 MB
    unsigned short* sbf = (unsigned short*)w; w += (size_t)N * D * sizeof(unsigned short);  // 12.8 MB
    unsigned short* BT  = (unsigned short*)w; w += 32768 * sizeof(unsigned short);          // 64 KB
    int* chist = (int*)w;            w += (size_t)NBMAX * sizeof(int);
    int* cbeg  = (int*)w;            w += (size_t)(NBMAX + 1) * sizeof(int);
    int* ccur  = (int*)w;            w += (size_t)NBMAX * sizeof(int);
    unsigned int* epk = (unsigned int*)w; w += (size_t)nE * sizeof(unsigned int);           // 3.2 MB

    hipMemsetAsync(chist, 0, (size_t)NBMAX * sizeof(int), stream);

    xbf_k<<<(N * D / 8 + 255) / 256, 256, 0, stream>>>(x, xbf, N * D / 8);
    bt_k<<<16, 256, 0, stream>>>(W, M, BT);

    int ebBlocks = (nE + CHUNK - 1) / CHUNK;     // 196
    cnt_k<<<ebBlocks, 256, 0, stream>>>(dst, nE, NB, chist);
    scanc_k<<<1, 64, 0, stream>>>(chist, NB, cbeg, ccur);
    part_k<<<ebBlocks, 256, 0, stream>>>(src, dst, nE, NB, ccur, epk);

    seg_k<<<NB, 512, 0, stream>>>(xbf, cbeg, epk, sbf, N);

    int gemmBlocks = (N + 63) / 64;              // 782
    gemm_mfma_k<<<gemmBlocks, 256, 0, stream>>>(xbf, sbf, BT, out, N);
}

// Round 8
// 177.223 us; speedup vs baseline: 4.6159x; 4.6159x over previous
//
#include <hip/hip_runtime.h>

#define D 128
#define COARSE 128          // nodes per coarse bin
#define NBMAX 400           // >= ceil(50000/128)=391
#define CHUNK 4096          // edges per block in cnt/part passes

typedef __attribute__((ext_vector_type(8))) short short8;
typedef __attribute__((ext_vector_type(8))) unsigned short ushort8;
typedef __attribute__((ext_vector_type(4))) float f32x4;

// round-to-nearest-even f32 -> bf16 bits
__device__ __forceinline__ unsigned short f2bf(float f) {
    unsigned u = __float_as_uint(f);
    unsigned r = (u + 0x7fffu + ((u >> 16) & 1u)) >> 16;
    return (unsigned short)r;
}

// ---------- 0. x -> bf16 copy (shared by seg gather + gemm A-stage) ----------
__global__ void xbf_k(const float* __restrict__ x, unsigned short* __restrict__ xbf,
                      int total8) {
    int i = blockIdx.x * 256 + threadIdx.x;      // one thread = 8 elements
    if (i >= total8) return;
    const float4* p = (const float4*)x + (size_t)i * 2;
    float4 a = p[0], b = p[1];
    ushort8 v;
    v[0] = f2bf(a.x); v[1] = f2bf(a.y); v[2] = f2bf(a.z); v[3] = f2bf(a.w);
    v[4] = f2bf(b.x); v[5] = f2bf(b.y); v[6] = f2bf(b.z); v[7] = f2bf(b.w);
    *(ushort8*)(xbf + (size_t)i * 8) = v;
}

// ---------- 1. prepass: B^T bf16. BT[col][k], k-contiguous per col ----------
__global__ void bt_k(const float* __restrict__ W, const float* __restrict__ M,
                     unsigned short* __restrict__ BT) {
    int g = blockIdx.x * 256 + threadIdx.x;     // 0..4095
    int col = g >> 5;
    int k0  = (g & 31) * 8;
    ushort8 hv;
#pragma unroll
    for (int j = 0; j < 8; ++j) {
        int k = k0 + j;
        float v = (k < 128) ? W[k * 128 + col] : M[(k - 128) * 128 + col];
        hv[j] = f2bf(v);
    }
    *(ushort8*)(BT + col * 256 + k0) = hv;
}

// ---------- 2. coarse histogram (LDS-privatized) ----------
__global__ void cnt_k(const int* __restrict__ dst, int nE, int NB,
                      int* __restrict__ chist) {
    __shared__ int lh[NBMAX];
    for (int t = threadIdx.x; t < NB; t += 256) lh[t] = 0;
    __syncthreads();
    int base = blockIdx.x * CHUNK;
#pragma unroll
    for (int r = 0; r < CHUNK / 256; ++r) {
        int i = base + r * 256 + threadIdx.x;
        if (i < nE) atomicAdd(&lh[dst[i] >> 7], 1);
    }
    __syncthreads();
    for (int t = threadIdx.x; t < NB; t += 256)
        if (lh[t]) atomicAdd(&chist[t], lh[t]);
}

// ---------- 3. scan coarse bins (single wave) ----------
__global__ void scanc_k(const int* __restrict__ chist, int NB,
                        int* __restrict__ cbeg, int* __restrict__ ccur) {
    int lane = threadIdx.x;
    if (lane >= 64) return;
    int carry = 0;
    int nch = (NB + 63) / 64;
    for (int c = 0; c < nch; ++c) {
        int i = c * 64 + lane;
        int v = (i < NB) ? chist[i] : 0;
        int incl = v;
#pragma unroll
        for (int off = 1; off < 64; off <<= 1) {
            int t = __shfl_up(incl, off, 64);
            if (lane >= off) incl += t;
        }
        int excl = carry + incl - v;
        if (i < NB) { cbeg[i] = excl; ccur[i] = excl; }
        carry += __shfl(incl, 63, 64);
    }
    if (lane == 0) cbeg[NB] = carry;
}

// ---------- 4. partition edges into coarse bins, packed (src16|dlow7) ----------
// One global atomic per (block,bin); each block's writes per bin contiguous.
__global__ void part_k(const int* __restrict__ src, const int* __restrict__ dst,
                       int nE, int NB, int* __restrict__ ccur,
                       unsigned int* __restrict__ epk) {
    __shared__ int lcnt[NBMAX];
    __shared__ int lbase[NBMAX];
    __shared__ int lcur[NBMAX];
    for (int t = threadIdx.x; t < NB; t += 256) { lcnt[t] = 0; lcur[t] = 0; }
    __syncthreads();
    int base = blockIdx.x * CHUNK;
#pragma unroll
    for (int r = 0; r < CHUNK / 256; ++r) {
        int i = base + r * 256 + threadIdx.x;
        if (i < nE) atomicAdd(&lcnt[dst[i] >> 7], 1);
    }
    __syncthreads();
    for (int t = threadIdx.x; t < NB; t += 256)
        if (lcnt[t]) lbase[t] = atomicAdd(&ccur[t], lcnt[t]);
    __syncthreads();
#pragma unroll
    for (int r = 0; r < CHUNK / 256; ++r) {
        int i = base + r * 256 + threadIdx.x;
        if (i < nE) {
            int d = dst[i], b = d >> 7;
            int rk = atomicAdd(&lcur[b], 1);
            epk[lbase[b] + rk] = (unsigned)(src[i] & 0xFFFF) | ((unsigned)(d & 127) << 16);
        }
    }
}

// ---------- 5. per-bin counting sort -> fine CSR (u16 src) ----------
// One block per coarse bin: 128-counter LDS counting sort of ~2046 edges.
// Emits eidx2 (u16 src, contiguous per node) + nbeg/ncnt per node.
__global__ void binsort_k(const unsigned int* __restrict__ epk,
                          const int* __restrict__ cbeg, int NB,
                          unsigned short* __restrict__ eidx2,
                          int* __restrict__ nbeg, int* __restrict__ ncnt,
                          int nNodes) {
    __shared__ int h[COARSE];
    __shared__ int base[COARSE];
    int b  = blockIdx.x;
    int e0 = cbeg[b], e1 = cbeg[b + 1];
    for (int t = threadIdx.x; t < COARSE; t += 256) h[t] = 0;
    __syncthreads();
    for (int e = e0 + threadIdx.x; e < e1; e += 256)
        atomicAdd(&h[(epk[e] >> 16) & 127], 1);
    __syncthreads();
    if (threadIdx.x == 0) {
        int acc = 0;
        for (int i = 0; i < COARSE; ++i) { base[i] = acc; acc += h[i]; }
    }
    __syncthreads();
    int rbase = b * COARSE;
    for (int t = threadIdx.x; t < COARSE; t += 256) {
        if (rbase + t < nNodes) { nbeg[rbase + t] = e0 + base[t]; ncnt[rbase + t] = h[t]; }
    }
    __syncthreads();
    for (int t = threadIdx.x; t < COARSE; t += 256) h[t] = 0;
    __syncthreads();
    for (int e = e0 + threadIdx.x; e < e1; e += 256) {
        unsigned pk = epk[e];
        int r = (pk >> 16) & 127;
        int p = atomicAdd(&h[r], 1);
        eidx2[e0 + base[r] + p] = (unsigned short)(pk & 0xFFFF);
    }
}

// ---------- 6. wave-per-node segment sum, bf16 gather, 4-deep ILP ----------
// Row gather: 64 lanes x u32 (2 bf16) = 256 B/row. Accumulate f32, store bf16.
__global__ void segsum_k(const unsigned short* __restrict__ xbf,
                         const int* __restrict__ nbeg, const int* __restrict__ ncnt,
                         const unsigned short* __restrict__ eidx2,
                         unsigned short* __restrict__ sbf, int nNodes) {
    int wave = (int)((blockIdx.x * (unsigned)blockDim.x + threadIdx.x) >> 6);
    int lane = threadIdx.x & 63;
    if (wave >= nNodes) return;
    int b = nbeg[wave];
    int e = b + ncnt[wave];
    const unsigned* xr = (const unsigned*)xbf;      // row j: xr[j*64 + lane]
    float2 a0 = make_float2(0.f, 0.f), a1 = a0, a2 = a0, a3 = a0;
    int k = b;
    for (; k + 4 <= e; k += 4) {
        int j0 = eidx2[k + 0];
        int j1 = eidx2[k + 1];
        int j2 = eidx2[k + 2];
        int j3 = eidx2[k + 3];
        unsigned v0 = xr[(size_t)j0 * 64 + lane];
        unsigned v1 = xr[(size_t)j1 * 64 + lane];
        unsigned v2 = xr[(size_t)j2 * 64 + lane];
        unsigned v3 = xr[(size_t)j3 * 64 + lane];
        a0.x += __uint_as_float(v0 << 16); a0.y += __uint_as_float(v0 & 0xFFFF0000u);
        a1.x += __uint_as_float(v1 << 16); a1.y += __uint_as_float(v1 & 0xFFFF0000u);
        a2.x += __uint_as_float(v2 << 16); a2.y += __uint_as_float(v2 & 0xFFFF0000u);
        a3.x += __uint_as_float(v3 << 16); a3.y += __uint_as_float(v3 & 0xFFFF0000u);
    }
    for (; k < e; ++k) {
        int j = eidx2[k];
        unsigned v = xr[(size_t)j * 64 + lane];
        a0.x += __uint_as_float(v << 16); a0.y += __uint_as_float(v & 0xFFFF0000u);
    }
    a0.x += a1.x + a2.x + a3.x;
    a0.y += a1.y + a2.y + a3.y;
    unsigned pk = (unsigned)f2bf(a0.x) | ((unsigned)f2bf(a0.y) << 16);
    ((unsigned*)(sbf + (size_t)wave * D))[lane] = pk;
}

// ---------- 7. out = relu([x|s] @ [W;M]) via bf16 MFMA (A staged from bf16) ----------
__global__ __launch_bounds__(256, 2) void gemm_mfma_k(
    const unsigned short* __restrict__ xbf, const unsigned short* __restrict__ sbf,
    const unsigned short* __restrict__ BT,
    float* __restrict__ out, int nNodes)
{
    __shared__ unsigned short Alds[64 * 256];   // [row][k] bf16, 32 KB
    char* Ab = (char*)Alds;

    const int tid  = threadIdx.x;
    const int lane = tid & 63;
    const int wv   = tid >> 6;          // 0..3
    const int r0   = blockIdx.x * 64;
    const int wcol = wv * 32;

    // ---- stage A = [xbf | sbf] rows r0..r0+63, swizzled: byte ^= (row&7)<<4 ----
#pragma unroll
    for (int h = 0; h < 2; ++h) {
        const unsigned short* srcp = h ? sbf : xbf;
#pragma unroll
        for (int it = 0; it < 4; ++it) {
            int q   = tid + it * 256;          // 0..1023 ushort8 slots
            int row = q >> 4;                  // 0..63
            int k8  = (q & 15) * 8;            // 0..120
            ushort8 v = (ushort8){0, 0, 0, 0, 0, 0, 0, 0};
            if (r0 + row < nNodes)
                v = *(const ushort8*)(srcp + (size_t)(r0 + row) * D + k8);
            int byte = (row * 512 + (h * 128 + k8) * 2) ^ ((row & 7) << 4);
            *(ushort8*)(Ab + byte) = v;
        }
    }
    __syncthreads();

    f32x4 acc[4][2];
#pragma unroll
    for (int rg = 0; rg < 4; ++rg)
#pragma unroll
        for (int cg = 0; cg < 2; ++cg)
            acc[rg][cg] = (f32x4){0.f, 0.f, 0.f, 0.f};

    const int l16  = lane & 15;
    const int lk8  = (lane >> 4) * 8;

#pragma unroll
    for (int t = 0; t < 8; ++t) {
        short8 bh[2];
#pragma unroll
        for (int cg = 0; cg < 2; ++cg) {
            int col = wcol + cg * 16 + l16;
            bh[cg] = *(const short8*)(BT + col * 256 + t * 32 + lk8);
        }
        short8 ah[4];
#pragma unroll
        for (int rg = 0; rg < 4; ++rg) {
            int row  = rg * 16 + l16;
            int byte = (row * 512 + (t * 32 + lk8) * 2) ^ ((row & 7) << 4);
            ah[rg] = *(const short8*)(Ab + byte);
        }
#pragma unroll
        for (int rg = 0; rg < 4; ++rg)
#pragma unroll
            for (int cg = 0; cg < 2; ++cg)
                acc[rg][cg] = __builtin_amdgcn_mfma_f32_16x16x32_bf16(ah[rg], bh[cg], acc[rg][cg], 0, 0, 0);
    }

    // ---- epilogue: relu + store. C/D: col = lane&15, row = (lane>>4)*4 + reg ----
    const int rowoff = (lane >> 4) * 4;
#pragma unroll
    for (int rg = 0; rg < 4; ++rg) {
#pragma unroll
        for (int r = 0; r < 4; ++r) {
            int row = r0 + rg * 16 + rowoff + r;
            if (row < nNodes) {
#pragma unroll
                for (int cg = 0; cg < 2; ++cg) {
                    float v = acc[rg][cg][r];
                    out[(size_t)row * D + wcol + cg * 16 + l16] = v > 0.f ? v : 0.f;
                }
            }
        }
    }
}

extern "C" void kernel_launch(void* const* d_in, const int* in_sizes, int n_in,
                              void* d_out, int out_size, void* d_ws, size_t ws_size,
                              hipStream_t stream) {
    const float* x = (const float*)d_in[0];
    const float* W = (const float*)d_in[1];
    const float* M = (const float*)d_in[2];
    const int* edges = (const int*)d_in[3];

    int N  = in_sizes[0] / D;        // 50000
    int nE = in_sizes[3] / 2;        // 800000
    const int* src = edges;          // edges[0, :]
    const int* dst = edges + nE;     // edges[1, :]
    float* out = (float*)d_out;
    int NB = (N + COARSE - 1) / COARSE;   // 391

    // workspace layout
    char* w = (char*)d_ws;
    unsigned short* xbf = (unsigned short*)w; w += (size_t)N * D * sizeof(unsigned short);  // 12.8 MB
    unsigned short* sbf = (unsigned short*)w; w += (size_t)N * D * sizeof(unsigned short);  // 12.8 MB
    unsigned short* BT  = (unsigned short*)w; w += 32768 * sizeof(unsigned short);          // 64 KB
    int* chist = (int*)w;            w += (size_t)NBMAX * sizeof(int);
    int* cbeg  = (int*)w;            w += (size_t)(NBMAX + 1) * sizeof(int);
    int* ccur  = (int*)w;            w += (size_t)NBMAX * sizeof(int);
    int* nbeg  = (int*)w;            w += (size_t)N * sizeof(int);
    int* ncnt  = (int*)w;            w += (size_t)N * sizeof(int);
    unsigned int* epk = (unsigned int*)w;      w += (size_t)nE * sizeof(unsigned int);      // 3.2 MB
    unsigned short* eidx2 = (unsigned short*)w; w += (size_t)nE * sizeof(unsigned short);   // 1.6 MB

    hipMemsetAsync(chist, 0, (size_t)NBMAX * sizeof(int), stream);

    xbf_k<<<(N * D / 8 + 255) / 256, 256, 0, stream>>>(x, xbf, N * D / 8);
    bt_k<<<16, 256, 0, stream>>>(W, M, BT);

    int ebBlocks = (nE + CHUNK - 1) / CHUNK;     // 196
    cnt_k<<<ebBlocks, 256, 0, stream>>>(dst, nE, NB, chist);
    scanc_k<<<1, 64, 0, stream>>>(chist, NB, cbeg, ccur);
    part_k<<<ebBlocks, 256, 0, stream>>>(src, dst, nE, NB, ccur, epk);
    binsort_k<<<NB, 256, 0, stream>>>(epk, cbeg, NB, eidx2, nbeg, ncnt, N);

    int segBlocks = (N * 64 + 255) / 256;        // one wave per node, 12500 blocks
    segsum_k<<<segBlocks, 256, 0, stream>>>(xbf, nbeg, ncnt, eidx2, sbf, N);

    int gemmBlocks = (N + 63) / 64;              // 782
    gemm_mfma_k<<<gemmBlocks, 256, 0, stream>>>(xbf, sbf, BT, out, N);
}

// Round 9
// 174.339 us; speedup vs baseline: 4.6923x; 1.0165x over previous
//
#include <hip/hip_runtime.h>

#define D 128
#define COARSE 128          // nodes per coarse bin
#define NBMAX 400           // >= ceil(50000/128)=391
#define CHUNK 4096          // edges per block in cnt/part passes

typedef __attribute__((ext_vector_type(8))) short short8;
typedef __attribute__((ext_vector_type(8))) unsigned short ushort8;
typedef __attribute__((ext_vector_type(4))) float f32x4;

// round-to-nearest-even f32 -> bf16 bits
__device__ __forceinline__ unsigned short f2bf(float f) {
    unsigned u = __float_as_uint(f);
    unsigned r = (u + 0x7fffu + ((u >> 16) & 1u)) >> 16;
    return (unsigned short)r;
}

// ---------- 0. fused prep: x -> bf16 copy  +  B^T bf16 ----------
// threads [0, total8): xbf 8-elem chunks; threads [total8, total8+4096): BT.
__global__ void prep_k(const float* __restrict__ x, unsigned short* __restrict__ xbf,
                       const float* __restrict__ W, const float* __restrict__ M,
                       unsigned short* __restrict__ BT, int total8) {
    int i = blockIdx.x * 256 + threadIdx.x;
    if (i < total8) {
        const float4* p = (const float4*)x + (size_t)i * 2;
        float4 a = p[0], b = p[1];
        ushort8 v;
        v[0] = f2bf(a.x); v[1] = f2bf(a.y); v[2] = f2bf(a.z); v[3] = f2bf(a.w);
        v[4] = f2bf(b.x); v[5] = f2bf(b.y); v[6] = f2bf(b.z); v[7] = f2bf(b.w);
        *(ushort8*)(xbf + (size_t)i * 8) = v;
    } else {
        int g = i - total8;                     // 0..4095
        if (g < 4096) {
            int col = g >> 5;
            int k0  = (g & 31) * 8;
            ushort8 hv;
#pragma unroll
            for (int j = 0; j < 8; ++j) {
                int k = k0 + j;
                float v = (k < 128) ? W[k * 128 + col] : M[(k - 128) * 128 + col];
                hv[j] = f2bf(v);
            }
            *(ushort8*)(BT + col * 256 + k0) = hv;
        }
    }
}

// ---------- 2. coarse histogram (LDS-privatized) ----------
__global__ void cnt_k(const int* __restrict__ dst, int nE, int NB,
                      int* __restrict__ chist) {
    __shared__ int lh[NBMAX];
    for (int t = threadIdx.x; t < NB; t += 256) lh[t] = 0;
    __syncthreads();
    int base = blockIdx.x * CHUNK;
#pragma unroll
    for (int r = 0; r < CHUNK / 256; ++r) {
        int i = base + r * 256 + threadIdx.x;
        if (i < nE) atomicAdd(&lh[dst[i] >> 7], 1);
    }
    __syncthreads();
    for (int t = threadIdx.x; t < NB; t += 256)
        if (lh[t]) atomicAdd(&chist[t], lh[t]);
}

// ---------- 3. scan coarse bins (single wave) ----------
__global__ void scanc_k(const int* __restrict__ chist, int NB,
                        int* __restrict__ cbeg, int* __restrict__ ccur) {
    int lane = threadIdx.x;
    if (lane >= 64) return;
    int carry = 0;
    int nch = (NB + 63) / 64;
    for (int c = 0; c < nch; ++c) {
        int i = c * 64 + lane;
        int v = (i < NB) ? chist[i] : 0;
        int incl = v;
#pragma unroll
        for (int off = 1; off < 64; off <<= 1) {
            int t = __shfl_up(incl, off, 64);
            if (lane >= off) incl += t;
        }
        int excl = carry + incl - v;
        if (i < NB) { cbeg[i] = excl; ccur[i] = excl; }
        carry += __shfl(incl, 63, 64);
    }
    if (lane == 0) cbeg[NB] = carry;
}

// ---------- 4. partition edges into coarse bins, packed (src16|dlow7) ----------
__global__ void part_k(const int* __restrict__ src, const int* __restrict__ dst,
                       int nE, int NB, int* __restrict__ ccur,
                       unsigned int* __restrict__ epk) {
    __shared__ int lcnt[NBMAX];
    __shared__ int lbase[NBMAX];
    __shared__ int lcur[NBMAX];
    for (int t = threadIdx.x; t < NB; t += 256) { lcnt[t] = 0; lcur[t] = 0; }
    __syncthreads();
    int base = blockIdx.x * CHUNK;
#pragma unroll
    for (int r = 0; r < CHUNK / 256; ++r) {
        int i = base + r * 256 + threadIdx.x;
        if (i < nE) atomicAdd(&lcnt[dst[i] >> 7], 1);
    }
    __syncthreads();
    for (int t = threadIdx.x; t < NB; t += 256)
        if (lcnt[t]) lbase[t] = atomicAdd(&ccur[t], lcnt[t]);
    __syncthreads();
#pragma unroll
    for (int r = 0; r < CHUNK / 256; ++r) {
        int i = base + r * 256 + threadIdx.x;
        if (i < nE) {
            int d = dst[i], b = d >> 7;
            int rk = atomicAdd(&lcur[b], 1);
            epk[lbase[b] + rk] = (unsigned)(src[i] & 0xFFFF) | ((unsigned)(d & 127) << 16);
        }
    }
}

// ---------- 5. per-bin counting sort -> fine CSR (u16 src) ----------
__global__ void binsort_k(const unsigned int* __restrict__ epk,
                          const int* __restrict__ cbeg, int NB,
                          unsigned short* __restrict__ eidx2,
                          int* __restrict__ nbeg, int* __restrict__ ncnt,
                          int nNodes) {
    __shared__ int h[COARSE];
    __shared__ int base[COARSE];
    int b  = blockIdx.x;
    int e0 = cbeg[b], e1 = cbeg[b + 1];
    for (int t = threadIdx.x; t < COARSE; t += 256) h[t] = 0;
    __syncthreads();
    for (int e = e0 + threadIdx.x; e < e1; e += 256)
        atomicAdd(&h[(epk[e] >> 16) & 127], 1);
    __syncthreads();
    // wave-parallel exclusive scan of h[0..127]: lanes 0..63 handle 2 bins each
    if (threadIdx.x < 64) {
        int lane = threadIdx.x;
        int v0 = h[lane], v1 = h[lane + 64];
        int i0 = v0;
#pragma unroll
        for (int off = 1; off < 64; off <<= 1) {
            int t = __shfl_up(i0, off, 64);
            if (lane >= off) i0 += t;
        }
        int tot0 = __shfl(i0, 63, 64);
        int i1 = v1;
#pragma unroll
        for (int off = 1; off < 64; off <<= 1) {
            int t = __shfl_up(i1, off, 64);
            if (lane >= off) i1 += t;
        }
        base[lane]      = i0 - v0;
        base[lane + 64] = tot0 + i1 - v1;
    }
    __syncthreads();
    int rbase = b * COARSE;
    for (int t = threadIdx.x; t < COARSE; t += 256) {
        if (rbase + t < nNodes) { nbeg[rbase + t] = e0 + base[t]; ncnt[rbase + t] = h[t]; }
    }
    __syncthreads();
    for (int t = threadIdx.x; t < COARSE; t += 256) h[t] = 0;
    __syncthreads();
    for (int e = e0 + threadIdx.x; e < e1; e += 256) {
        unsigned pk = epk[e];
        int r = (pk >> 16) & 127;
        int p = atomicAdd(&h[r], 1);
        eidx2[e0 + base[r] + p] = (unsigned short)(pk & 0xFFFF);
    }
}

// ---------- 6. wave-per-node segment sum, bf16 gather, 8-deep ILP ----------
__global__ void segsum_k(const unsigned short* __restrict__ xbf,
                         const int* __restrict__ nbeg, const int* __restrict__ ncnt,
                         const unsigned short* __restrict__ eidx2,
                         unsigned short* __restrict__ sbf, int nNodes) {
    int wave = (int)((blockIdx.x * (unsigned)blockDim.x + threadIdx.x) >> 6);
    int lane = threadIdx.x & 63;
    if (wave >= nNodes) return;
    int b = nbeg[wave];
    int e = b + ncnt[wave];
    const unsigned* xr = (const unsigned*)xbf;      // row j: xr[j*64 + lane]
    float2 acc[8];
#pragma unroll
    for (int u = 0; u < 8; ++u) acc[u] = make_float2(0.f, 0.f);
    int k = b;
    for (; k + 8 <= e; k += 8) {
        int j[8];
#pragma unroll
        for (int u = 0; u < 8; ++u) j[u] = eidx2[k + u];
        unsigned v[8];
#pragma unroll
        for (int u = 0; u < 8; ++u) v[u] = xr[(size_t)j[u] * 64 + lane];
#pragma unroll
        for (int u = 0; u < 8; ++u) {
            acc[u].x += __uint_as_float(v[u] << 16);
            acc[u].y += __uint_as_float(v[u] & 0xFFFF0000u);
        }
    }
    for (; k + 4 <= e; k += 4) {
        int j[4];
#pragma unroll
        for (int u = 0; u < 4; ++u) j[u] = eidx2[k + u];
#pragma unroll
        for (int u = 0; u < 4; ++u) {
            unsigned v = xr[(size_t)j[u] * 64 + lane];
            acc[u].x += __uint_as_float(v << 16);
            acc[u].y += __uint_as_float(v & 0xFFFF0000u);
        }
    }
    for (; k < e; ++k) {
        int j = eidx2[k];
        unsigned v = xr[(size_t)j * 64 + lane];
        acc[0].x += __uint_as_float(v << 16);
        acc[0].y += __uint_as_float(v & 0xFFFF0000u);
    }
#pragma unroll
    for (int u = 1; u < 8; ++u) { acc[0].x += acc[u].x; acc[0].y += acc[u].y; }
    unsigned pk = (unsigned)f2bf(acc[0].x) | ((unsigned)f2bf(acc[0].y) << 16);
    ((unsigned*)(sbf + (size_t)wave * D))[lane] = pk;
}

// ---------- 7. out = relu([x|s] @ [W;M]) via bf16 MFMA (A staged from bf16) ----------
__global__ __launch_bounds__(256, 2) void gemm_mfma_k(
    const unsigned short* __restrict__ xbf, const unsigned short* __restrict__ sbf,
    const unsigned short* __restrict__ BT,
    float* __restrict__ out, int nNodes)
{
    __shared__ unsigned short Alds[64 * 256];   // [row][k] bf16, 32 KB
    char* Ab = (char*)Alds;

    const int tid  = threadIdx.x;
    const int lane = tid & 63;
    const int wv   = tid >> 6;          // 0..3
    const int r0   = blockIdx.x * 64;
    const int wcol = wv * 32;

    // ---- stage A = [xbf | sbf] rows r0..r0+63, swizzled: byte ^= (row&7)<<4 ----
#pragma unroll
    for (int h = 0; h < 2; ++h) {
        const unsigned short* srcp = h ? sbf : xbf;
#pragma unroll
        for (int it = 0; it < 4; ++it) {
            int q   = tid + it * 256;          // 0..1023 ushort8 slots
            int row = q >> 4;                  // 0..63
            int k8  = (q & 15) * 8;            // 0..120
            ushort8 v = (ushort8){0, 0, 0, 0, 0, 0, 0, 0};
            if (r0 + row < nNodes)
                v = *(const ushort8*)(srcp + (size_t)(r0 + row) * D + k8);
            int byte = (row * 512 + (h * 128 + k8) * 2) ^ ((row & 7) << 4);
            *(ushort8*)(Ab + byte) = v;
        }
    }
    __syncthreads();

    f32x4 acc[4][2];
#pragma unroll
    for (int rg = 0; rg < 4; ++rg)
#pragma unroll
        for (int cg = 0; cg < 2; ++cg)
            acc[rg][cg] = (f32x4){0.f, 0.f, 0.f, 0.f};

    const int l16  = lane & 15;
    const int lk8  = (lane >> 4) * 8;

#pragma unroll
    for (int t = 0; t < 8; ++t) {
        short8 bh[2];
#pragma unroll
        for (int cg = 0; cg < 2; ++cg) {
            int col = wcol + cg * 16 + l16;
            bh[cg] = *(const short8*)(BT + col * 256 + t * 32 + lk8);
        }
        short8 ah[4];
#pragma unroll
        for (int rg = 0; rg < 4; ++rg) {
            int row  = rg * 16 + l16;
            int byte = (row * 512 + (t * 32 + lk8) * 2) ^ ((row & 7) << 4);
            ah[rg] = *(const short8*)(Ab + byte);
        }
#pragma unroll
        for (int rg = 0; rg < 4; ++rg)
#pragma unroll
            for (int cg = 0; cg < 2; ++cg)
                acc[rg][cg] = __builtin_amdgcn_mfma_f32_16x16x32_bf16(ah[rg], bh[cg], acc[rg][cg], 0, 0, 0);
    }

    // ---- epilogue: relu + store. C/D: col = lane&15, row = (lane>>4)*4 + reg ----
    const int rowoff = (lane >> 4) * 4;
#pragma unroll
    for (int rg = 0; rg < 4; ++rg) {
#pragma unroll
        for (int r = 0; r < 4; ++r) {
            int row = r0 + rg * 16 + rowoff + r;
            if (row < nNodes) {
#pragma unroll
                for (int cg = 0; cg < 2; ++cg) {
                    float v = acc[rg][cg][r];
                    out[(size_t)row * D + wcol + cg * 16 + l16] = v > 0.f ? v : 0.f;
                }
            }
        }
    }
}

extern "C" void kernel_launch(void* const* d_in, const int* in_sizes, int n_in,
                              void* d_out, int out_size, void* d_ws, size_t ws_size,
                              hipStream_t stream) {
    const float* x = (const float*)d_in[0];
    const float* W = (const float*)d_in[1];
    const float* M = (const float*)d_in[2];
    const int* edges = (const int*)d_in[3];

    int N  = in_sizes[0] / D;        // 50000
    int nE = in_sizes[3] / 2;        // 800000
    const int* src = edges;          // edges[0, :]
    const int* dst = edges + nE;     // edges[1, :]
    float* out = (float*)d_out;
    int NB = (N + COARSE - 1) / COARSE;   // 391

    // workspace layout
    char* w = (char*)d_ws;
    unsigned short* xbf = (unsigned short*)w; w += (size_t)N * D * sizeof(unsigned short);  // 12.8 MB
    unsigned short* sbf = (unsigned short*)w; w += (size_t)N * D * sizeof(unsigned short);  // 12.8 MB
    unsigned short* BT  = (unsigned short*)w; w += 32768 * sizeof(unsigned short);          // 64 KB
    int* chist = (int*)w;            w += (size_t)NBMAX * sizeof(int);
    int* cbeg  = (int*)w;            w += (size_t)(NBMAX + 1) * sizeof(int);
    int* ccur  = (int*)w;            w += (size_t)NBMAX * sizeof(int);
    int* nbeg  = (int*)w;            w += (size_t)N * sizeof(int);
    int* ncnt  = (int*)w;            w += (size_t)N * sizeof(int);
    unsigned int* epk = (unsigned int*)w;      w += (size_t)nE * sizeof(unsigned int);      // 3.2 MB
    unsigned short* eidx2 = (unsigned short*)w; w += (size_t)nE * sizeof(unsigned short);   // 1.6 MB

    hipMemsetAsync(chist, 0, (size_t)NBMAX * sizeof(int), stream);

    int total8 = N * D / 8;                       // 800000
    prep_k<<<(total8 + 4096 + 255) / 256, 256, 0, stream>>>(x, xbf, W, M, BT, total8);

    int ebBlocks = (nE + CHUNK - 1) / CHUNK;     // 196
    cnt_k<<<ebBlocks, 256, 0, stream>>>(dst, nE, NB, chist);
    scanc_k<<<1, 64, 0, stream>>>(chist, NB, cbeg, ccur);
    part_k<<<ebBlocks, 256, 0, stream>>>(src, dst, nE, NB, ccur, epk);
    binsort_k<<<NB, 256, 0, stream>>>(epk, cbeg, NB, eidx2, nbeg, ncnt, N);

    int segBlocks = (N * 64 + 255) / 256;        // one wave per node, 12500 blocks
    segsum_k<<<segBlocks, 256, 0, stream>>>(xbf, nbeg, ncnt, eidx2, sbf, N);

    int gemmBlocks = (N + 63) / 64;              // 782
    gemm_mfma_k<<<gemmBlocks, 256, 0, stream>>>(xbf, sbf, BT, out, N);
}